// Round 9
// baseline (251.454 us; speedup 1.0000x reference)
//
#include <hip/hip_runtime.h>
#include <hip/hip_cooperative_groups.h>
#include <hip/hip_fp16.h>
#include <math.h>

namespace cg = cooperative_groups;

// Problem constants (from reference):
//   B=4, N=1024 -> 4096 atoms; IN_CH=OUT_CH=16; N_BASIS=16; N_FEAT=19
//   centers = linspace(0,3.5,16) -> c_f = f*(3.5/15); GAMMA = 3.5/16
//   out /= sqrt(24)
#define IN_CH 16
#define OUT_CH 16
#define N_BASIS 16
#define N_FEAT 19                    // 16 basis + 3 rhat
#define Y_STRIDE (N_FEAT * OUT_CH)   // 304 halfs per atom, layout y[a][f][o]
#define GAMMA_INV (16.0f / 3.5f)
#define CENTER_STEP (3.5f / 15.0f)
#define INV_SQRT_NNORM 0.20412414523193154f  // 1/sqrt(24), folded into y
#define APB 16                       // atoms per block (fallback kernel A)
#define EPB 64                       // edges per block (4 x 16-edge windows)

// ---------------------------------------------------------------------------
// FUSED cooperative kernel: phase A (y precompute, spread over all blocks)
// -> grid.sync() -> phase B (R8's proven edge scatter). One dispatch instead
// of two: removes a launch gap; phases A/B use the same proven memory
// patterns as R8 (coalesced y[a][f][o] fp16, channel-fast half2x2 gather,
// windowed dedup with O(1) run-boundary leader test).
// ---------------------------------------------------------------------------
__global__ __launch_bounds__(256) void fused_conv(
    const float* __restrict__ x, const float* __restrict__ W,
    const float* __restrict__ edge_vec, const int* __restrict__ edge_src,
    const int* __restrict__ edge_dst, __half* __restrict__ y,
    float* __restrict__ out, int E, int n_atoms, int apb) {
  __shared__ float xs[4][IN_CH];
  __shared__ float feat[EPB][20];     // stride 20 floats: conflict-benign
  __shared__ float4 msg4[EPB][4];     // msg4[s][h] = channels {4h..4h+3}
  __shared__ int dsts[EPB];

  const int t = threadIdx.x;

  // ================= Phase A: y[a,f,o] = (1/sqrt24) * W[f,o,:] . x[a,:] ====
  // Thread t owns y-row t (= f*16+o) and, for t<48, row 256+t. W rows live
  // in registers across the block's atoms. Blocks cover atoms [a0, a0+apb).
  {
    const int a0 = blockIdx.x * apb;
    const int aEnd = min(a0 + apb, n_atoms);
    if (a0 < aEnd) {
      const float4* w4a = (const float4*)(W + t * IN_CH);
      float4 w0 = w4a[0], w1 = w4a[1], w2 = w4a[2], w3 = w4a[3];
      float4 u0, u1, u2, u3;
      if (t < Y_STRIDE - 256) {
        const float4* w4b = (const float4*)(W + (256 + t) * IN_CH);
        u0 = w4b[0]; u1 = w4b[1]; u2 = w4b[2]; u3 = w4b[3];
      }
      for (int base = a0; base < aEnd; base += 4) {
        const int cnt = min(4, aEnd - base);
        __syncthreads();
        if (t < cnt * IN_CH) {
          xs[t >> 4][t & 15] = x[base * IN_CH + t];
          out[base * IN_CH + t] = 0.0f;  // zero output (harness poisons)
        }
        __syncthreads();
        for (int al = 0; al < cnt; ++al) {
          const float* xv = xs[al];
          float acc =
              w0.x * xv[0] + w0.y * xv[1] + w0.z * xv[2] + w0.w * xv[3] +
              w1.x * xv[4] + w1.y * xv[5] + w1.z * xv[6] + w1.w * xv[7] +
              w2.x * xv[8] + w2.y * xv[9] + w2.z * xv[10] + w2.w * xv[11] +
              w3.x * xv[12] + w3.y * xv[13] + w3.z * xv[14] + w3.w * xv[15];
          y[(size_t)(base + al) * Y_STRIDE + t] =
              __float2half(acc * INV_SQRT_NNORM);
          if (t < Y_STRIDE - 256) {
            float acc2 =
                u0.x * xv[0] + u0.y * xv[1] + u0.z * xv[2] + u0.w * xv[3] +
                u1.x * xv[4] + u1.y * xv[5] + u1.z * xv[6] + u1.w * xv[7] +
                u2.x * xv[8] + u2.y * xv[9] + u2.z * xv[10] + u2.w * xv[11] +
                u3.x * xv[12] + u3.y * xv[13] + u3.z * xv[14] + u3.w * xv[15];
            y[(size_t)(base + al) * Y_STRIDE + 256 + t] =
                __float2half(acc2 * INV_SQRT_NNORM);
          }
        }
      }
    }
  }

  cg::this_grid().sync();

  // ================= Phase B: edge scatter (R8 body) =======================
  // 4 lanes/edge, 4 channels/lane, channel index FAST (proven coalescing).
  const int h = t & 3;                // channel quad {4h..4h+3}
  const int el = (t >> 2) & 15;       // edge within window
  const int w = t >> 6;               // window 0..3
  const int s = w * 16 + el;          // slot 0..63
  const int e = blockIdx.x * EPB + s;
  const bool valid = (e < E);

  float vx = 0.f, vy = 0.f, vz = 0.f;
  int src = 0;
  if (valid) {
    vx = edge_vec[3 * e + 0];
    vy = edge_vec[3 * e + 1];
    vz = edge_vec[3 * e + 2];
    src = edge_src[e];
    if (h == 0) dsts[s] = edge_dst[e];
  } else if (h == 0) {
    dsts[s] = -1 - s;  // unique sentinel: never merged, never emitted
  }
  const float r = sqrtf(vx * vx + vy * vy + vz * vz);

#pragma unroll
  for (int j = 0; j < 4; ++j) {
    const float tb = (r - CENTER_STEP * (float)(4 * h + j)) * GAMMA_INV;
    feat[s][4 * h + j] = __expf(-tb * tb);
  }
  if (h < 3) {
    // reference: rhat = where(r > 1e-10, vec / max(r,1e-10), 0)
    const float inv = (r > 1e-10f) ? (1.0f / r) : 0.0f;
    const float comp = (h == 0) ? vx : ((h == 1) ? vy : vz);
    feat[s][N_BASIS + h] = comp * inv;
  }
  __syncthreads();

  float a0 = 0.f, a1 = 0.f, a2 = 0.f, a3 = 0.f;
  if (valid) {
    // y[src][f][4h..4h+3]: one 8-B load per feature; lanes h=0..3 cover
    // 32 B contiguous per feature -> coalesced.
    const float2* __restrict__ yrow =
        (const float2*)(y + (size_t)src * Y_STRIDE + 4 * h);
#pragma unroll
    for (int f = 0; f < N_FEAT; ++f) {
      const float2 raw = yrow[f * (OUT_CH / 4)];
      const float2 v0 = __half22float2(*(const __half2*)&raw.x);
      const float2 v1 = __half22float2(*(const __half2*)&raw.y);
      const float ff = feat[s][f];
      a0 += ff * v0.x;
      a1 += ff * v0.y;
      a2 += ff * v1.x;
      a3 += ff * v1.y;
    }
  }
  msg4[s][h] = make_float4(a0, a1, a2, a3);
  __syncthreads();

  // Run-boundary dedup: leader = first slot of a contiguous same-dst run
  // (O(1) test). Leader sums its run (predicated, unrolled) and emits.
  const int wb = w * 16;
  const int mydst = dsts[s];
  const bool lead = (el == 0) || (dsts[s - 1] != mydst);
  if (lead && mydst >= 0) {
    float4 m = msg4[s][h];
    float s0 = m.x, s1 = m.y, s2 = m.z, s3 = m.w;
    bool run = true;
#pragma unroll
    for (int k = 1; k < 16; ++k) {
      const int kk = el + k;
      run = run && (kk < 16) && (dsts[wb + kk] == mydst);
      if (run) {
        m = msg4[wb + kk][h];
        s0 += m.x; s1 += m.y; s2 += m.z; s3 += m.w;
      }
    }
    float* base = &out[mydst * OUT_CH + 4 * h];
    atomicAdd(base + 0, s0);   // 1/sqrt(24) already folded into y
    atomicAdd(base + 1, s1);
    atomicAdd(base + 2, s2);
    atomicAdd(base + 3, s3);
  }
}

// ===========================================================================
// Fallback path (R8, known-good): used if cooperative launch is unavailable.
// ===========================================================================
__global__ __launch_bounds__(320) void precompute_y(
    const float* __restrict__ x, const float* __restrict__ W,
    __half* __restrict__ y, float* __restrict__ out, int n_atoms) {
  __shared__ float xs[APB][IN_CH];
  const int t = threadIdx.x;
  const int a0 = blockIdx.x * APB;

  if (t < APB * IN_CH) {
    const int idx = a0 * IN_CH + t;
    const bool ok = idx < n_atoms * IN_CH;
    xs[t >> 4][t & 15] = ok ? x[idx] : 0.0f;
    if (ok) out[idx] = 0.0f;
  }

  float4 w0, w1, w2, w3;
  if (t < Y_STRIDE) {
    const float4* w4 = (const float4*)(W + t * IN_CH);
    w0 = w4[0]; w1 = w4[1]; w2 = w4[2]; w3 = w4[3];
  }
  __syncthreads();

  if (t < Y_STRIDE) {
#pragma unroll
    for (int al = 0; al < APB; ++al) {
      if (a0 + al >= n_atoms) break;
      const float* xv = xs[al];
      float acc = w0.x * xv[0] + w0.y * xv[1] + w0.z * xv[2] + w0.w * xv[3] +
                  w1.x * xv[4] + w1.y * xv[5] + w1.z * xv[6] + w1.w * xv[7] +
                  w2.x * xv[8] + w2.y * xv[9] + w2.z * xv[10] + w2.w * xv[11] +
                  w3.x * xv[12] + w3.y * xv[13] + w3.z * xv[14] + w3.w * xv[15];
      y[(size_t)(a0 + al) * Y_STRIDE + t] = __float2half(acc * INV_SQRT_NNORM);
    }
  }
}

__global__ __launch_bounds__(256) void edge_scatter(
    const __half* __restrict__ y, const float* __restrict__ edge_vec,
    const int* __restrict__ edge_src, const int* __restrict__ edge_dst,
    float* __restrict__ out, int E) {
  __shared__ float feat[EPB][20];
  __shared__ float4 msg4[EPB][4];
  __shared__ int dsts[EPB];

  const int t = threadIdx.x;
  const int h = t & 3;
  const int el = (t >> 2) & 15;
  const int w = t >> 6;
  const int s = w * 16 + el;
  const int e = blockIdx.x * EPB + s;
  const bool valid = (e < E);

  float vx = 0.f, vy = 0.f, vz = 0.f;
  int src = 0;
  if (valid) {
    vx = edge_vec[3 * e + 0];
    vy = edge_vec[3 * e + 1];
    vz = edge_vec[3 * e + 2];
    src = edge_src[e];
    if (h == 0) dsts[s] = edge_dst[e];
  } else if (h == 0) {
    dsts[s] = -1 - s;
  }
  const float r = sqrtf(vx * vx + vy * vy + vz * vz);

#pragma unroll
  for (int j = 0; j < 4; ++j) {
    const float tb = (r - CENTER_STEP * (float)(4 * h + j)) * GAMMA_INV;
    feat[s][4 * h + j] = __expf(-tb * tb);
  }
  if (h < 3) {
    const float inv = (r > 1e-10f) ? (1.0f / r) : 0.0f;
    const float comp = (h == 0) ? vx : ((h == 1) ? vy : vz);
    feat[s][N_BASIS + h] = comp * inv;
  }
  __syncthreads();

  float a0 = 0.f, a1 = 0.f, a2 = 0.f, a3 = 0.f;
  if (valid) {
    const float2* __restrict__ yrow =
        (const float2*)(y + (size_t)src * Y_STRIDE + 4 * h);
#pragma unroll
    for (int f = 0; f < N_FEAT; ++f) {
      const float2 raw = yrow[f * (OUT_CH / 4)];
      const float2 v0 = __half22float2(*(const __half2*)&raw.x);
      const float2 v1 = __half22float2(*(const __half2*)&raw.y);
      const float ff = feat[s][f];
      a0 += ff * v0.x;
      a1 += ff * v0.y;
      a2 += ff * v1.x;
      a3 += ff * v1.y;
    }
  }
  msg4[s][h] = make_float4(a0, a1, a2, a3);
  __syncthreads();

  const int wb = w * 16;
  const int mydst = dsts[s];
  const bool lead = (el == 0) || (dsts[s - 1] != mydst);
  if (lead && mydst >= 0) {
    float4 m = msg4[s][h];
    float s0 = m.x, s1 = m.y, s2 = m.z, s3 = m.w;
    bool run = true;
#pragma unroll
    for (int k = 1; k < 16; ++k) {
      const int kk = el + k;
      run = run && (kk < 16) && (dsts[wb + kk] == mydst);
      if (run) {
        m = msg4[wb + kk][h];
        s0 += m.x; s1 += m.y; s2 += m.z; s3 += m.w;
      }
    }
    float* base = &out[mydst * OUT_CH + 4 * h];
    atomicAdd(base + 0, s0);
    atomicAdd(base + 1, s1);
    atomicAdd(base + 2, s2);
    atomicAdd(base + 3, s3);
  }
}

extern "C" void kernel_launch(void* const* d_in, const int* in_sizes, int n_in,
                              void* d_out, int out_size, void* d_ws,
                              size_t ws_size, hipStream_t stream) {
  const float* x = (const float*)d_in[0];        // [n_atoms, 16]
  const float* W = (const float*)d_in[1];        // [19, 16, 16]
  const float* edge_vec = (const float*)d_in[2]; // [E, 3]
  const int* edge_src = (const int*)d_in[3];     // [E]
  const int* edge_dst = (const int*)d_in[4];     // [E]
  float* out = (float*)d_out;

  int E = in_sizes[3];
  int n_atoms = in_sizes[0] / IN_CH;
  __half* y = (__half*)d_ws;

  int nblk = (E + EPB - 1) / EPB;
  int apb = (n_atoms + nblk - 1) / nblk;

  // Try the fused single-dispatch cooperative kernel first.
  void* args[] = {(void*)&x,        (void*)&W,   (void*)&edge_vec,
                  (void*)&edge_src, (void*)&edge_dst, (void*)&y,
                  (void*)&out,      (void*)&E,   (void*)&n_atoms,
                  (void*)&apb};
  hipError_t err = hipLaunchCooperativeKernel(
      (const void*)fused_conv, dim3(nblk), dim3(256), args, 0, stream);
  if (err == hipSuccess) return;

  // Fallback: R8 two-kernel path.
  precompute_y<<<(n_atoms + APB - 1) / APB, 320, 0, stream>>>(x, W, y, out,
                                                              n_atoms);
  edge_scatter<<<nblk, 256, 0, stream>>>(y, edge_vec, edge_src, edge_dst, out,
                                         E);
}

// Round 10
// 76.412 us; speedup vs baseline: 3.2908x; 3.2908x over previous
//
#include <hip/hip_runtime.h>
#include <hip/hip_fp16.h>
#include <math.h>

// Problem constants (from reference):
//   B=4, N=1024 -> 4096 atoms; IN_CH=OUT_CH=16; N_BASIS=16; N_FEAT=19
//   centers = linspace(0,3.5,16) -> c_f = f*(3.5/15); GAMMA = 3.5/16
//   out /= sqrt(24)
//
// Session finding (R9 decomposition): harness floor ≈ 77 µs (268 MB d_ws
// poison fill ~43 µs @ 80% HBM peak + d_out poison + input restores + graph
// gaps). This two-kernel structure (R8) runs ≈ 0-2 µs above that floor.
// Cooperative grid.sync() measured ~165 µs of spin on MI355X at 1600 blocks
// (R9) — do not fuse via cooperative launch.
#define IN_CH 16
#define OUT_CH 16
#define N_BASIS 16
#define N_FEAT 19                    // 16 basis + 3 rhat
#define Y_STRIDE (N_FEAT * OUT_CH)   // 304 halfs per atom, layout y[a][f][o]
#define GAMMA_INV (16.0f / 3.5f)
#define CENTER_STEP (3.5f / 15.0f)
#define INV_SQRT_NNORM 0.20412414523193154f  // 1/sqrt(24), folded into y
#define APB 16                       // atoms per block in kernel A
#define EPB 64                       // edges per block in kernel B (4 windows)

// ---------------------------------------------------------------------------
// Kernel A: y[a,f,o] = (1/sqrt24)*sum_i W[f,o,i]*x[a,i], fp16, layout [a][f][o]
// 16 atoms per block; thread t's W row W[f,o,:] (t = f*16+o) loaded ONCE into
// registers, reused across 16 atoms. Stores coalesced (608 B/atom). Also
// zeroes out (harness poisons d_out before every timed launch).
// ---------------------------------------------------------------------------
__global__ __launch_bounds__(320) void precompute_y(
    const float* __restrict__ x, const float* __restrict__ W,
    __half* __restrict__ y, float* __restrict__ out, int n_atoms) {
  __shared__ float xs[APB][IN_CH];
  const int t = threadIdx.x;
  const int a0 = blockIdx.x * APB;

  if (t < APB * IN_CH) {
    const int idx = a0 * IN_CH + t;
    const bool ok = idx < n_atoms * IN_CH;
    xs[t >> 4][t & 15] = ok ? x[idx] : 0.0f;
    if (ok) out[idx] = 0.0f;  // zero output (poisoned before every launch)
  }

  float4 w0, w1, w2, w3;
  if (t < Y_STRIDE) {
    const float4* w4 = (const float4*)(W + t * IN_CH);  // t = f*16 + o
    w0 = w4[0]; w1 = w4[1]; w2 = w4[2]; w3 = w4[3];
  }
  __syncthreads();

  if (t < Y_STRIDE) {
#pragma unroll
    for (int al = 0; al < APB; ++al) {
      if (a0 + al >= n_atoms) break;
      const float* xv = xs[al];
      float acc = w0.x * xv[0] + w0.y * xv[1] + w0.z * xv[2] + w0.w * xv[3] +
                  w1.x * xv[4] + w1.y * xv[5] + w1.z * xv[6] + w1.w * xv[7] +
                  w2.x * xv[8] + w2.y * xv[9] + w2.z * xv[10] + w2.w * xv[11] +
                  w3.x * xv[12] + w3.y * xv[13] + w3.z * xv[14] + w3.w * xv[15];
      // fold 1/sqrt(24) before fp16 rounding (~5x smaller abs error)
      y[(size_t)(a0 + al) * Y_STRIDE + t] = __float2half(acc * INV_SQRT_NNORM);
    }
  }
}

// ---------------------------------------------------------------------------
// Kernel B: msg[e,o] = sum_f feat[e,f] * y[src_e,f,o] -> atomicAdd out[dst].
// 4 lanes/edge, 4 channels/lane, CHANNEL index FAST (coalescing proven in
// R5/R7/R8; edge-fast mapping cost +13 µs in R6). Lanes 0-3 of an edge read
// 32 B contiguous per feature as one dwordx2 each. Dedup: fully-unrolled
// 16-slot window scan (edge list is dst-sorted within each periodic-shift
// chunk); unique (dst,channel) pairs emit fp32 atomics.
// ---------------------------------------------------------------------------
__global__ __launch_bounds__(256) void edge_scatter(
    const __half* __restrict__ y, const float* __restrict__ edge_vec,
    const int* __restrict__ edge_src, const int* __restrict__ edge_dst,
    float* __restrict__ out, int E) {
  __shared__ float feat[EPB][20];     // stride 20 floats: conflict-benign
  __shared__ float4 msg4[EPB][4];     // msg4[s][h] = channels {4h..4h+3}
  __shared__ int dsts[EPB];

  const int t = threadIdx.x;
  const int h = t & 3;                // FAST: channel quad {4h..4h+3}
  const int el = (t >> 2) & 15;       // edge within window
  const int w = t >> 6;               // window 0..3
  const int s = w * 16 + el;          // slot 0..63
  const int e = blockIdx.x * EPB + s;
  const bool valid = (e < E);

  float vx = 0.f, vy = 0.f, vz = 0.f;
  int src = 0;
  if (valid) {
    vx = edge_vec[3 * e + 0];
    vy = edge_vec[3 * e + 1];
    vz = edge_vec[3 * e + 2];
    src = edge_src[e];
    if (h == 0) dsts[s] = edge_dst[e];
  } else if (h == 0) {
    dsts[s] = -1 - s;  // unique sentinel: never merged, never emitted
  }
  const float r = sqrtf(vx * vx + vy * vy + vz * vz);

  // basis features 4h..4h+3: exp(-((r - c)/gamma)^2)
#pragma unroll
  for (int j = 0; j < 4; ++j) {
    const float tb = (r - CENTER_STEP * (float)(4 * h + j)) * GAMMA_INV;
    feat[s][4 * h + j] = __expf(-tb * tb);
  }
  if (h < 3) {
    // reference: rhat = where(r > 1e-10, vec / max(r,1e-10), 0)
    const float inv = (r > 1e-10f) ? (1.0f / r) : 0.0f;
    const float comp = (h == 0) ? vx : ((h == 1) ? vy : vz);
    feat[s][N_BASIS + h] = comp * inv;
  }
  __syncthreads();

  float a0 = 0.f, a1 = 0.f, a2 = 0.f, a3 = 0.f;
  if (valid) {
    // y[src][f][4h..4h+3]: one 8-B load per feature (addr 8-B aligned:
    // src*608 + 8h bytes). Lanes h=0..3 cover 32 B contiguous -> coalesced.
    const float2* __restrict__ yrow =
        (const float2*)(y + (size_t)src * Y_STRIDE + 4 * h);
#pragma unroll
    for (int f = 0; f < N_FEAT; ++f) {
      const float2 raw = yrow[f * (OUT_CH / 4)];
      const __half2 p0 = *(const __half2*)&raw.x;
      const __half2 p1 = *(const __half2*)&raw.y;
      const float2 v0 = __half22float2(p0);
      const float2 v1 = __half22float2(p1);
      const float ff = feat[s][f];
      a0 += ff * v0.x;
      a1 += ff * v0.y;
      a2 += ff * v1.x;
      a3 += ff * v1.y;
    }
  }
  msg4[s][h] = make_float4(a0, a1, a2, a3);
  __syncthreads();

  // Fixed-window dedup (fully unrolled, no serial walks) + atomic emit.
  const int wb = w * 16;
  const int mydst = dsts[s];
  int leader = el;
#pragma unroll
  for (int k = 0; k < 16; ++k) {
    if (dsts[wb + k] == mydst) { leader = k; break; }
  }
  if (leader == el && mydst >= 0) {
    float s0 = 0.f, s1 = 0.f, s2 = 0.f, s3 = 0.f;
#pragma unroll
    for (int k = 0; k < 16; ++k) {
      if (k >= el && dsts[wb + k] == mydst) {
        const float4 m = msg4[wb + k][h];
        s0 += m.x; s1 += m.y; s2 += m.z; s3 += m.w;
      }
    }
    float* base = &out[mydst * OUT_CH + 4 * h];
    atomicAdd(base + 0, s0);   // 1/sqrt(24) already folded into y
    atomicAdd(base + 1, s1);
    atomicAdd(base + 2, s2);
    atomicAdd(base + 3, s3);
  }
}

// ---------------------------------------------------------------------------
// Fallback (only if ws too small for y): direct per-edge evaluation.
// ---------------------------------------------------------------------------
__global__ __launch_bounds__(256) void edge_direct(
    const float* __restrict__ x, const float* __restrict__ W,
    const float* __restrict__ edge_vec, const int* __restrict__ edge_src,
    const int* __restrict__ edge_dst, float* __restrict__ out, int E) {
  __shared__ float Ws[N_FEAT * OUT_CH * IN_CH];
  __shared__ float feat[16][N_FEAT];
  __shared__ float xs[16][IN_CH];

  const int t = threadIdx.x;
  for (int i = t; i < N_FEAT * OUT_CH * IN_CH; i += 256) Ws[i] = W[i];

  const int eg = t >> 4;
  const int o = t & 15;
  const int e = blockIdx.x * 16 + eg;
  const bool valid = (e < E);

  float vx = 0.f, vy = 0.f, vz = 0.f;
  int src = 0, dst = 0;
  if (valid) {
    vx = edge_vec[3 * e + 0];
    vy = edge_vec[3 * e + 1];
    vz = edge_vec[3 * e + 2];
    src = edge_src[e];
    dst = edge_dst[e];
    xs[eg][o] = x[src * IN_CH + o];
  }
  const float r = sqrtf(vx * vx + vy * vy + vz * vz);
  const float tt = (r - CENTER_STEP * (float)o) * GAMMA_INV;
  feat[eg][o] = __expf(-tt * tt);
  if (o < 3) {
    const float inv = (r > 1e-10f) ? (1.0f / r) : 0.0f;
    const float comp = (o == 0) ? vx : ((o == 1) ? vy : vz);
    feat[eg][N_BASIS + o] = comp * inv;
  }
  __syncthreads();

  if (valid) {
    float acc = 0.f;
#pragma unroll
    for (int f = 0; f < N_FEAT; ++f) {
      const float* wrow = &Ws[(f * OUT_CH + o) * IN_CH];
      float dot = 0.f;
#pragma unroll
      for (int i = 0; i < IN_CH; ++i) dot += wrow[i] * xs[eg][i];
      acc += feat[eg][f] * dot;
    }
    atomicAdd(&out[dst * OUT_CH + o], acc * INV_SQRT_NNORM);
  }
}

extern "C" void kernel_launch(void* const* d_in, const int* in_sizes, int n_in,
                              void* d_out, int out_size, void* d_ws,
                              size_t ws_size, hipStream_t stream) {
  const float* x = (const float*)d_in[0];        // [n_atoms, 16]
  const float* W = (const float*)d_in[1];        // [19, 16, 16]
  const float* edge_vec = (const float*)d_in[2]; // [E, 3]
  const int* edge_src = (const int*)d_in[3];     // [E]
  const int* edge_dst = (const int*)d_in[4];     // [E]
  float* out = (float*)d_out;

  const int E = in_sizes[3];
  const int n_atoms = in_sizes[0] / IN_CH;

  const size_t y_bytes = (size_t)n_atoms * Y_STRIDE * sizeof(__half);
  if (ws_size >= y_bytes) {
    __half* y = (__half*)d_ws;
    precompute_y<<<(n_atoms + APB - 1) / APB, 320, 0, stream>>>(x, W, y, out,
                                                               n_atoms);
    edge_scatter<<<(E + EPB - 1) / EPB, 256, 0, stream>>>(y, edge_vec, edge_src,
                                                          edge_dst, out, E);
  } else {
    hipMemsetAsync(out, 0, (size_t)out_size * sizeof(float), stream);
    edge_direct<<<(E + 15) / 16, 256, 0, stream>>>(x, W, edge_vec, edge_src,
                                                   edge_dst, out, E);
  }
}